// Round 1
// baseline (659.198 us; speedup 1.0000x reference)
//
#include <hip/hip_runtime.h>
#include <hip/hip_bf16.h>

#define T_LEN 1024
#define D_DIM 64
#define BATCH 32

// ---------------------------------------------------------------------------
// Kernel 1: pairwise Euclidean distance, GEMM-trick.
// 64(M) x 128(N) tile, 256 threads, 8x4 micro-tile per thread.
// ps row-major (A reads are 2-address broadcasts), ts k-major pad 132
// (B reads are contiguous conflict-free b128). k unrolled x4 so A-frag
// loads are b128 along k. K-summation order identical to previous kernel
// (sequential k, fmac) -> bit-identical cost matrix.
// grid (8, 16, gb), block 256.
// ---------------------------------------------------------------------------
#define BM 64
#define BN 128

__global__ __launch_bounds__(256, 3) void cost_kernel(const float* __restrict__ pred,
                                                      const float* __restrict__ targ,
                                                      float* __restrict__ cost) {
    const int b = blockIdx.z;
    const float* P = pred + (size_t)b * T_LEN * D_DIM;
    const float* Tg = targ + (size_t)b * T_LEN * D_DIM;
    float* C = cost + (size_t)b * T_LEN * T_LEN;
    const int row0 = blockIdx.y * BM;
    const int col0 = blockIdx.x * BN;

    __shared__ __align__(16) float ps[BM][D_DIM + 4];   // row-major, stride 68 (16B-aligned rows)
    __shared__ __align__(16) float ts[D_DIM][BN + 4];   // k-major, stride 132 (16B-aligned rows)
    __shared__ float p2[BM], t2[BN];

    const int tid = threadIdx.x;

    // ---- stage pred: 64 rows x 16 float4 chunks = 1024 -> 4 iters, direct copy (b128 LDS writes)
#pragma unroll
    for (int it = 0; it < 4; ++it) {
        int f = tid + 256 * it;          // 0..1023
        int row = f >> 4;                // 0..63
        int kc = f & 15;                 // float4 chunk
        float4 v = *(const float4*)(P + (size_t)(row0 + row) * D_DIM + 4 * kc);
        *(float4*)&ps[row][4 * kc] = v;
    }
    // ---- stage targ transposed: 128 rows x 16 chunks = 2048 -> 8 iters
#pragma unroll
    for (int it = 0; it < 8; ++it) {
        int f = tid + 256 * it;          // 0..2047
        int col = f >> 4;                // 0..127 (targ row = C column)
        int kc = f & 15;
        float4 w = *(const float4*)(Tg + (size_t)(col0 + col) * D_DIM + 4 * kc);
        ts[4 * kc + 0][col] = w.x;
        ts[4 * kc + 1][col] = w.y;
        ts[4 * kc + 2][col] = w.z;
        ts[4 * kc + 3][col] = w.w;
    }
    __syncthreads();

    // ---- squared norms (same sequential-k accumulation order as before)
    if (tid < 64) {
        float s = 0.0f;
        const float4* pr = (const float4*)&ps[tid][0];
#pragma unroll
        for (int q = 0; q < 16; ++q) {
            float4 v = pr[q];
            s += v.x * v.x; s += v.y * v.y; s += v.z * v.z; s += v.w * v.w;
        }
        p2[tid] = s;
    } else if (tid < 192) {
        int c = tid - 64;                // 0..127
        float s = 0.0f;
#pragma unroll
        for (int k = 0; k < 64; ++k) { float x = ts[k][c]; s += x * x; }
        t2[c] = s;
    }
    __syncthreads();

    // ---- 8x4 micro-tile GEMM
    const int tx = tid & 31;             // 32 col-groups of 4
    const int ty = tid >> 5;             // 8 row-groups of 8
    const int r0 = 8 * ty, c0 = 4 * tx;

    float acc[8][4];
#pragma unroll
    for (int i = 0; i < 8; ++i)
#pragma unroll
        for (int j = 0; j < 4; ++j) acc[i][j] = 0.0f;

#pragma unroll
    for (int k4 = 0; k4 < 16; ++k4) {
        float4 b0 = *(const float4*)&ts[4 * k4 + 0][c0];
        float4 b1 = *(const float4*)&ts[4 * k4 + 1][c0];
        float4 b2 = *(const float4*)&ts[4 * k4 + 2][c0];
        float4 b3 = *(const float4*)&ts[4 * k4 + 3][c0];
#pragma unroll
        for (int i = 0; i < 8; ++i) {
            float4 a = *(const float4*)&ps[r0 + i][4 * k4];
            acc[i][0] += a.x * b0.x; acc[i][1] += a.x * b0.y; acc[i][2] += a.x * b0.z; acc[i][3] += a.x * b0.w;
            acc[i][0] += a.y * b1.x; acc[i][1] += a.y * b1.y; acc[i][2] += a.y * b1.z; acc[i][3] += a.y * b1.w;
            acc[i][0] += a.z * b2.x; acc[i][1] += a.z * b2.y; acc[i][2] += a.z * b2.z; acc[i][3] += a.z * b2.w;
            acc[i][0] += a.w * b3.x; acc[i][1] += a.w * b3.y; acc[i][2] += a.w * b3.z; acc[i][3] += a.w * b3.w;
        }
    }

    // ---- epilogue
    float4 tt = *(const float4*)&t2[c0];
#pragma unroll
    for (int i = 0; i < 8; ++i) {
        float pa = p2[r0 + i];
        float4 o;
        o.x = sqrtf(fmaxf(pa + tt.x - 2.0f * acc[i][0], 1e-12f));
        o.y = sqrtf(fmaxf(pa + tt.y - 2.0f * acc[i][1], 1e-12f));
        o.z = sqrtf(fmaxf(pa + tt.z - 2.0f * acc[i][2], 1e-12f));
        o.w = sqrtf(fmaxf(pa + tt.w - 2.0f * acc[i][3], 1e-12f));
        *(float4*)(C + (size_t)(row0 + r0 + i) * T_LEN + (col0 + c0)) = o;
    }
}

// ---------------------------------------------------------------------------
// Kernel 2: Frechet DP, one wave per batch, time-skewed pipeline.
// Prefetch now goes through an LDS ring (12 slots x 4KB) filled by
// global_load_lds (zero VGPR cost, genuinely 12 steps deep), consumed with
// counted s_waitcnt vmcnt(44). Layout [slot][chunk][lane][16B] matches the
// wave-uniform-base + lane*16 write rule of global_load_lds; readback is a
// contiguous 1KB wave read -> conflict-free ds_read_b128.
// ---------------------------------------------------------------------------
#define RD 12

__device__ __forceinline__ void gl_lds16(const float* g, void* l) {
    __builtin_amdgcn_global_load_lds(
        (const __attribute__((address_space(1))) unsigned int*)(const void*)g,
        (__attribute__((address_space(3))) unsigned int*)l, 16, 0, 0);
}

__global__ __launch_bounds__(64) void dp_kernel(const float* __restrict__ cost,
                                                float* __restrict__ out) {
    const int b = blockIdx.x;
    const int t = threadIdx.x;  // lane 0..63
    const float INF = __builtin_inff();
    const float* C = cost + (size_t)b * T_LEN * T_LEN + 16 * t;

    __shared__ __align__(16) float4 ring[RD][4][64];  // 48 KB

    float prev[16];
#pragma unroll
    for (int j = 0; j < 16; ++j) prev[j] = INF;
    float right_out = INF;
    float diag_feed = INF;

    // prologue: fill all RD slots (steps 0..RD-1); 48 loads outstanding
#pragma unroll
    for (int d = 0; d < RD; ++d) {
        int r = d - t; r = r < 0 ? 0 : (r > T_LEN - 1 ? T_LEN - 1 : r);
        const float* src = C + (size_t)r * T_LEN;
#pragma unroll
        for (int q = 0; q < 4; ++q) gl_lds16(src + 4 * q, &ring[d][q][0]);
    }

    const int S = T_LEN + 63;                 // 1087 real steps
    const int NCH = (S + RD - 1) / RD;        // 91 chunks -> 1092 steps (tail is guarded no-op)
    int s = 0;
    for (int chunk = 0; chunk < NCH; ++chunk) {
#pragma unroll
        for (int u = 0; u < RD; ++u, ++s) {
            // slot u holds step s (s % RD == u). Oldest 4 loads must be done.
            asm volatile("s_waitcnt vmcnt(44)" ::: "memory");
            __builtin_amdgcn_sched_barrier(0);
            float4 c0 = ring[u][0][t];
            float4 c1 = ring[u][1][t];
            float4 c2 = ring[u][2][t];
            float4 c3 = ring[u][3][t];

            int r = s - t;
            float inc = __shfl_up(right_out, 1, 64);
            float left = inc, diag = diag_feed;
            diag_feed = inc;
            if (t == 0) { left = (r == 0) ? -INF : INF; diag = INF; }
            if (r >= 0 && r < T_LEN) {
                float cb[16] = {c0.x, c0.y, c0.z, c0.w, c1.x, c1.y, c1.z, c1.w,
                                c2.x, c2.y, c2.z, c2.w, c3.x, c3.y, c3.z, c3.w};
#pragma unroll
                for (int j = 0; j < 16; ++j) {
                    float c = cb[j];
                    float up = prev[j];
                    float v = fmaxf(c, fminf(fminf(up, diag), left));
                    diag = up; left = v; prev[j] = v;
                }
                right_out = left;
            }
            // refill slot u with step s+RD (consumed above; loads return >=200cy later)
            {
                int rn = s + RD - t; rn = rn < 0 ? 0 : (rn > T_LEN - 1 ? T_LEN - 1 : rn);
                const float* src = C + (size_t)rn * T_LEN;
#pragma unroll
                for (int q = 0; q < 4; ++q) gl_lds16(src + 4 * q, &ring[u][q][0]);
            }
        }
    }
    asm volatile("s_waitcnt vmcnt(0)" ::: "memory");
    if (t == 63) atomicAdd(out, prev[15] * (1.0f / (float)BATCH));
}

// ---------------------------------------------------------------------------
// Fallback: fused DP computing distances on the fly (only if ws can't hold
// one 4 MB cost matrix). Unchanged.
// ---------------------------------------------------------------------------
__global__ __launch_bounds__(64) void dp_fused_kernel(const float* __restrict__ pred,
                                                      const float* __restrict__ targ,
                                                      float* __restrict__ out) {
    const int b = blockIdx.x;
    const int t = threadIdx.x;
    const float INF = __builtin_inff();
    const float* P = pred + (size_t)b * T_LEN * D_DIM;
    const float* T = targ + (size_t)b * T_LEN * D_DIM + (size_t)(16 * t) * D_DIM;

    float prev[16];
#pragma unroll
    for (int j = 0; j < 16; ++j) prev[j] = INF;
    float right_out = INF;
    float diag_feed = INF;

    for (int s = 0; s < T_LEN + 63; s++) {
        int r = s - t;
        float inc = __shfl_up(right_out, 1, 64);
        float left = inc, diag = diag_feed;
        diag_feed = inc;
        if (t == 0) { left = (r == 0) ? -INF : INF; diag = INF; }
        if (r >= 0 && r < T_LEN) {
            float4 pr[16];
            const float4* pp = (const float4*)(P + (size_t)r * D_DIM);
#pragma unroll
            for (int q = 0; q < 16; q++) pr[q] = pp[q];
#pragma unroll
            for (int j = 0; j < 16; j++) {
                const float4* tp = (const float4*)(T + (size_t)j * D_DIM);
                float acc = 0.0f;
#pragma unroll
                for (int q = 0; q < 16; q++) {
                    float4 tv = tp[q];
                    float dx = pr[q].x - tv.x; acc += dx * dx;
                    float dy = pr[q].y - tv.y; acc += dy * dy;
                    float dz = pr[q].z - tv.z; acc += dz * dz;
                    float dw = pr[q].w - tv.w; acc += dw * dw;
                }
                float c = sqrtf(fmaxf(acc, 1e-12f));
                float up = prev[j];
                float v = fmaxf(c, fminf(fminf(up, diag), left));
                diag = up; left = v; prev[j] = v;
            }
            right_out = left;
        }
    }
    if (t == 63) atomicAdd(out, prev[15] * (1.0f / (float)BATCH));
}

extern "C" void kernel_launch(void* const* d_in, const int* in_sizes, int n_in,
                              void* d_out, int out_size, void* d_ws, size_t ws_size,
                              hipStream_t stream) {
    const float* pred = (const float*)d_in[0];
    const float* targ = (const float*)d_in[1];
    float* out = (float*)d_out;

    hipMemsetAsync(out, 0, sizeof(float) * out_size, stream);

    const size_t per_batch = (size_t)T_LEN * T_LEN * sizeof(float);  // 4 MB
    int bpg = (int)(ws_size / per_batch);
    if (bpg > BATCH) bpg = BATCH;

    if (bpg >= 1) {
        float* cost = (float*)d_ws;
        for (int g0 = 0; g0 < BATCH; g0 += bpg) {
            int gb = (BATCH - g0) < bpg ? (BATCH - g0) : bpg;
            dim3 grid(T_LEN / BN, T_LEN / BM, gb);
            cost_kernel<<<grid, 256, 0, stream>>>(pred + (size_t)g0 * T_LEN * D_DIM,
                                                  targ + (size_t)g0 * T_LEN * D_DIM,
                                                  cost);
            dp_kernel<<<gb, 64, 0, stream>>>(cost, out);
        }
    } else {
        dp_fused_kernel<<<BATCH, 64, 0, stream>>>(pred, targ, out);
    }
}

// Round 2
// 342.489 us; speedup vs baseline: 1.9247x; 1.9247x over previous
//
#include <hip/hip_runtime.h>
#include <hip/hip_bf16.h>

#define T_LEN 1024
#define D_DIM 64
#define BATCH 32

// ---------------------------------------------------------------------------
// Kernel 1: pairwise Euclidean distance, GEMM-trick.
// 64(M) x 128(N) tile, 256 threads, 8x4 micro-tile per thread. Unchanged
// from round 1 (isolating the dp_kernel fix this round).
// ---------------------------------------------------------------------------
#define BM 64
#define BN 128

__global__ __launch_bounds__(256, 3) void cost_kernel(const float* __restrict__ pred,
                                                      const float* __restrict__ targ,
                                                      float* __restrict__ cost) {
    const int b = blockIdx.z;
    const float* P = pred + (size_t)b * T_LEN * D_DIM;
    const float* Tg = targ + (size_t)b * T_LEN * D_DIM;
    float* C = cost + (size_t)b * T_LEN * T_LEN;
    const int row0 = blockIdx.y * BM;
    const int col0 = blockIdx.x * BN;

    __shared__ __align__(16) float ps[BM][D_DIM + 4];   // row-major, stride 68
    __shared__ __align__(16) float ts[D_DIM][BN + 4];   // k-major, stride 132
    __shared__ float p2[BM], t2[BN];

    const int tid = threadIdx.x;

#pragma unroll
    for (int it = 0; it < 4; ++it) {
        int f = tid + 256 * it;
        int row = f >> 4;
        int kc = f & 15;
        float4 v = *(const float4*)(P + (size_t)(row0 + row) * D_DIM + 4 * kc);
        *(float4*)&ps[row][4 * kc] = v;
    }
#pragma unroll
    for (int it = 0; it < 8; ++it) {
        int f = tid + 256 * it;
        int col = f >> 4;
        int kc = f & 15;
        float4 w = *(const float4*)(Tg + (size_t)(col0 + col) * D_DIM + 4 * kc);
        ts[4 * kc + 0][col] = w.x;
        ts[4 * kc + 1][col] = w.y;
        ts[4 * kc + 2][col] = w.z;
        ts[4 * kc + 3][col] = w.w;
    }
    __syncthreads();

    if (tid < 64) {
        float s = 0.0f;
        const float4* pr = (const float4*)&ps[tid][0];
#pragma unroll
        for (int q = 0; q < 16; ++q) {
            float4 v = pr[q];
            s += v.x * v.x; s += v.y * v.y; s += v.z * v.z; s += v.w * v.w;
        }
        p2[tid] = s;
    } else if (tid < 192) {
        int c = tid - 64;
        float s = 0.0f;
#pragma unroll
        for (int k = 0; k < 64; ++k) { float x = ts[k][c]; s += x * x; }
        t2[c] = s;
    }
    __syncthreads();

    const int tx = tid & 31;
    const int ty = tid >> 5;
    const int r0 = 8 * ty, c0 = 4 * tx;

    float acc[8][4];
#pragma unroll
    for (int i = 0; i < 8; ++i)
#pragma unroll
        for (int j = 0; j < 4; ++j) acc[i][j] = 0.0f;

#pragma unroll
    for (int k4 = 0; k4 < 16; ++k4) {
        float4 b0 = *(const float4*)&ts[4 * k4 + 0][c0];
        float4 b1 = *(const float4*)&ts[4 * k4 + 1][c0];
        float4 b2 = *(const float4*)&ts[4 * k4 + 2][c0];
        float4 b3 = *(const float4*)&ts[4 * k4 + 3][c0];
#pragma unroll
        for (int i = 0; i < 8; ++i) {
            float4 a = *(const float4*)&ps[r0 + i][4 * k4];
            acc[i][0] += a.x * b0.x; acc[i][1] += a.x * b0.y; acc[i][2] += a.x * b0.z; acc[i][3] += a.x * b0.w;
            acc[i][0] += a.y * b1.x; acc[i][1] += a.y * b1.y; acc[i][2] += a.y * b1.z; acc[i][3] += a.y * b1.w;
            acc[i][0] += a.z * b2.x; acc[i][1] += a.z * b2.y; acc[i][2] += a.z * b2.z; acc[i][3] += a.z * b2.w;
            acc[i][0] += a.w * b3.x; acc[i][1] += a.w * b3.y; acc[i][2] += a.w * b3.z; acc[i][3] += a.w * b3.w;
        }
    }

    float4 tt = *(const float4*)&t2[c0];
#pragma unroll
    for (int i = 0; i < 8; ++i) {
        float pa = p2[r0 + i];
        float4 o;
        o.x = sqrtf(fmaxf(pa + tt.x - 2.0f * acc[i][0], 1e-12f));
        o.y = sqrtf(fmaxf(pa + tt.y - 2.0f * acc[i][1], 1e-12f));
        o.z = sqrtf(fmaxf(pa + tt.z - 2.0f * acc[i][2], 1e-12f));
        o.w = sqrtf(fmaxf(pa + tt.w - 2.0f * acc[i][3], 1e-12f));
        *(float4*)(C + (size_t)(row0 + r0 + i) * T_LEN + (col0 + c0)) = o;
    }
}

// ---------------------------------------------------------------------------
// Kernel 2: Frechet DP, one wave per batch, time-skewed pipeline.
// LDS ring (12 slots x 4KB) filled by global_load_lds. Ring reads are
// inline-asm ds_read_b128 on raw 32-bit LDS offsets -> INVISIBLE to the
// compiler's waitcnt pass, so it cannot insert the conservative vmcnt(0)
// drain that killed round 1. Counted s_waitcnt vmcnt(40) is the only vmem
// wait in the loop (steady state: (RD-2)*4 = 40 loads legitimately in
// flight). LDS->reg is double-buffered one step ahead; lgkmcnt(0) +
// sched_barrier(0) at step top per rule #18.
// ---------------------------------------------------------------------------
#define RD 12

__device__ __forceinline__ void gl_lds16(const float* g, void* l) {
    __builtin_amdgcn_global_load_lds(
        (const __attribute__((address_space(1))) unsigned int*)(const void*)g,
        (__attribute__((address_space(3))) unsigned int*)l, 16, 0, 0);
}

__device__ __forceinline__ float4 lds_read_b128(unsigned off) {
    float4 r;
    asm volatile("ds_read_b128 %0, %1" : "=v"(r) : "v"(off));
    return r;
}

__global__ __launch_bounds__(64) void dp_kernel(const float* __restrict__ cost,
                                                float* __restrict__ out) {
    const int b = blockIdx.x;
    const int t = threadIdx.x;  // lane 0..63
    const float INF = __builtin_inff();
    const float* C = cost + (size_t)b * T_LEN * T_LEN + 16 * t;

    __shared__ __align__(16) float4 ring[RD][4][64];  // 48 KB

    const unsigned ring_base =
        (unsigned)(size_t)(__attribute__((address_space(3))) void*)&ring[0][0][0];
    const unsigned my_off = ring_base + 16u * (unsigned)t;

    float prev[16];
#pragma unroll
    for (int j = 0; j < 16; ++j) prev[j] = INF;
    float right_out = INF;
    float diag_feed = INF;

    // prologue: fill all RD slots (steps 0..RD-1); 48 loads outstanding
#pragma unroll
    for (int d = 0; d < RD; ++d) {
        int r = d - t; r = r < 0 ? 0 : (r > T_LEN - 1 ? T_LEN - 1 : r);
        const float* src = C + (size_t)r * T_LEN;
#pragma unroll
        for (int q = 0; q < 4; ++q) gl_lds16(src + 4 * q, &ring[d][q][0]);
    }

    // pre-read slot 0 into regs A (slot0 writes done once vmcnt <= 44)
    float4 rA0, rA1, rA2, rA3, rB0, rB1, rB2, rB3;
    asm volatile("s_waitcnt vmcnt(44)" ::: "memory");
    __builtin_amdgcn_sched_barrier(0);
    rA0 = lds_read_b128(my_off + 0);
    rA1 = lds_read_b128(my_off + 1024);
    rA2 = lds_read_b128(my_off + 2048);
    rA3 = lds_read_b128(my_off + 3072);

    const int S = T_LEN + 63;                 // 1087 real steps
    const int NCH = (S + RD - 1) / RD;        // 91 chunks (tail steps are guarded no-ops)
    int s = 0;

#define DP_STEP(C0, C1, C2, C3, N0, N1, N2, N3, USLOT)                        \
    {                                                                         \
        asm volatile("s_waitcnt lgkmcnt(0)" ::: "memory");                    \
        __builtin_amdgcn_sched_barrier(0);                                    \
        const int r = s - t;                                                  \
        float inc = __shfl_up(right_out, 1, 64);                              \
        float left = inc, diag = diag_feed;                                   \
        diag_feed = inc;                                                      \
        if (t == 0) { left = (r == 0) ? -INF : INF; diag = INF; }             \
        if (r >= 0 && r < T_LEN) {                                            \
            float cb[16] = {C0.x, C0.y, C0.z, C0.w, C1.x, C1.y, C1.z, C1.w,   \
                            C2.x, C2.y, C2.z, C2.w, C3.x, C3.y, C3.z, C3.w};  \
            _Pragma("unroll")                                                 \
            for (int j = 0; j < 16; ++j) {                                    \
                float c = cb[j];                                              \
                float up = prev[j];                                           \
                float v = fmaxf(c, fminf(fminf(up, diag), left));             \
                diag = up; left = v; prev[j] = v;                             \
            }                                                                 \
            right_out = left;                                                 \
        }                                                                     \
        __builtin_amdgcn_sched_barrier(0);                                    \
        asm volatile("s_waitcnt vmcnt(40)" ::: "memory");                     \
        __builtin_amdgcn_sched_barrier(0);                                    \
        {                                                                     \
            const unsigned nb = my_off + ((((USLOT) + 1) % RD) * 4096u);      \
            N0 = lds_read_b128(nb + 0);                                       \
            N1 = lds_read_b128(nb + 1024);                                    \
            N2 = lds_read_b128(nb + 2048);                                    \
            N3 = lds_read_b128(nb + 3072);                                    \
            int rn = s + RD - t;                                              \
            rn = rn < 0 ? 0 : (rn > T_LEN - 1 ? T_LEN - 1 : rn);              \
            const float* src = C + (size_t)rn * T_LEN;                        \
            gl_lds16(src + 0,  &ring[USLOT][0][0]);                           \
            gl_lds16(src + 4,  &ring[USLOT][1][0]);                           \
            gl_lds16(src + 8,  &ring[USLOT][2][0]);                           \
            gl_lds16(src + 12, &ring[USLOT][3][0]);                           \
        }                                                                     \
        ++s;                                                                  \
    }

    for (int chunk = 0; chunk < NCH; ++chunk) {
        DP_STEP(rA0, rA1, rA2, rA3, rB0, rB1, rB2, rB3, 0)
        DP_STEP(rB0, rB1, rB2, rB3, rA0, rA1, rA2, rA3, 1)
        DP_STEP(rA0, rA1, rA2, rA3, rB0, rB1, rB2, rB3, 2)
        DP_STEP(rB0, rB1, rB2, rB3, rA0, rA1, rA2, rA3, 3)
        DP_STEP(rA0, rA1, rA2, rA3, rB0, rB1, rB2, rB3, 4)
        DP_STEP(rB0, rB1, rB2, rB3, rA0, rA1, rA2, rA3, 5)
        DP_STEP(rA0, rA1, rA2, rA3, rB0, rB1, rB2, rB3, 6)
        DP_STEP(rB0, rB1, rB2, rB3, rA0, rA1, rA2, rA3, 7)
        DP_STEP(rA0, rA1, rA2, rA3, rB0, rB1, rB2, rB3, 8)
        DP_STEP(rB0, rB1, rB2, rB3, rA0, rA1, rA2, rA3, 9)
        DP_STEP(rA0, rA1, rA2, rA3, rB0, rB1, rB2, rB3, 10)
        DP_STEP(rB0, rB1, rB2, rB3, rA0, rA1, rA2, rA3, 11)
    }
#undef DP_STEP

    asm volatile("s_waitcnt vmcnt(0) lgkmcnt(0)" ::: "memory");
    if (t == 63) atomicAdd(out, prev[15] * (1.0f / (float)BATCH));
}

// ---------------------------------------------------------------------------
// Fallback: fused DP computing distances on the fly (only if ws can't hold
// one 4 MB cost matrix). Unchanged.
// ---------------------------------------------------------------------------
__global__ __launch_bounds__(64) void dp_fused_kernel(const float* __restrict__ pred,
                                                      const float* __restrict__ targ,
                                                      float* __restrict__ out) {
    const int b = blockIdx.x;
    const int t = threadIdx.x;
    const float INF = __builtin_inff();
    const float* P = pred + (size_t)b * T_LEN * D_DIM;
    const float* T = targ + (size_t)b * T_LEN * D_DIM + (size_t)(16 * t) * D_DIM;

    float prev[16];
#pragma unroll
    for (int j = 0; j < 16; ++j) prev[j] = INF;
    float right_out = INF;
    float diag_feed = INF;

    for (int s = 0; s < T_LEN + 63; s++) {
        int r = s - t;
        float inc = __shfl_up(right_out, 1, 64);
        float left = inc, diag = diag_feed;
        diag_feed = inc;
        if (t == 0) { left = (r == 0) ? -INF : INF; diag = INF; }
        if (r >= 0 && r < T_LEN) {
            float4 pr[16];
            const float4* pp = (const float4*)(P + (size_t)r * D_DIM);
#pragma unroll
            for (int q = 0; q < 16; q++) pr[q] = pp[q];
#pragma unroll
            for (int j = 0; j < 16; j++) {
                const float4* tp = (const float4*)(T + (size_t)j * D_DIM);
                float acc = 0.0f;
#pragma unroll
                for (int q = 0; q < 16; q++) {
                    float4 tv = tp[q];
                    float dx = pr[q].x - tv.x; acc += dx * dx;
                    float dy = pr[q].y - tv.y; acc += dy * dy;
                    float dz = pr[q].z - tv.z; acc += dz * dz;
                    float dw = pr[q].w - tv.w; acc += dw * dw;
                }
                float c = sqrtf(fmaxf(acc, 1e-12f));
                float up = prev[j];
                float v = fmaxf(c, fminf(fminf(up, diag), left));
                diag = up; left = v; prev[j] = v;
            }
            right_out = left;
        }
    }
    if (t == 63) atomicAdd(out, prev[15] * (1.0f / (float)BATCH));
}

extern "C" void kernel_launch(void* const* d_in, const int* in_sizes, int n_in,
                              void* d_out, int out_size, void* d_ws, size_t ws_size,
                              hipStream_t stream) {
    const float* pred = (const float*)d_in[0];
    const float* targ = (const float*)d_in[1];
    float* out = (float*)d_out;

    hipMemsetAsync(out, 0, sizeof(float) * out_size, stream);

    const size_t per_batch = (size_t)T_LEN * T_LEN * sizeof(float);  // 4 MB
    int bpg = (int)(ws_size / per_batch);
    if (bpg > BATCH) bpg = BATCH;

    if (bpg >= 1) {
        float* cost = (float*)d_ws;
        for (int g0 = 0; g0 < BATCH; g0 += bpg) {
            int gb = (BATCH - g0) < bpg ? (BATCH - g0) : bpg;
            dim3 grid(T_LEN / BN, T_LEN / BM, gb);
            cost_kernel<<<grid, 256, 0, stream>>>(pred + (size_t)g0 * T_LEN * D_DIM,
                                                  targ + (size_t)g0 * T_LEN * D_DIM,
                                                  cost);
            dp_kernel<<<gb, 64, 0, stream>>>(cost, out);
        }
    } else {
        dp_fused_kernel<<<BATCH, 64, 0, stream>>>(pred, targ, out);
    }
}